// Round 11
// baseline (331.371 us; speedup 1.0000x reference)
//
#include <hip/hip_runtime.h>

#define IN_F   100
#define HID_F  128
#define OUT_F  47

typedef short bf16x8 __attribute__((ext_vector_type(8)));
typedef short bf16x4 __attribute__((ext_vector_type(4)));
typedef float f32x4  __attribute__((ext_vector_type(4)));
typedef unsigned short u16;
typedef unsigned int   u32;

__device__ __forceinline__ u16 f2bf(float f) {
    u32 u = __float_as_uint(f);
    u += 0x7FFFu + ((u >> 16) & 1u);           // RNE
    return (u16)(u >> 16);
}
__device__ __forceinline__ float bf2f(u16 b) { return __uint_as_float(((u32)b) << 16); }
__device__ __forceinline__ float lo2f(u32 v) { return __uint_as_float(v << 16); }
__device__ __forceinline__ float hi2f(u32 v) { return __uint_as_float(v & 0xFFFF0000u); }

__device__ __forceinline__ void fma8(float* a, float wt, int4 v) {
    a[0] += wt * lo2f(v.x); a[1] += wt * hi2f(v.x);
    a[2] += wt * lo2f(v.y); a[3] += wt * hi2f(v.y);
    a[4] += wt * lo2f(v.z); a[5] += wt * hi2f(v.z);
    a[6] += wt * lo2f(v.w); a[7] += wt * hi2f(v.w);
}

// ---------------------------------------------------------------------------
// CSR build
// ---------------------------------------------------------------------------
__global__ void count_kernel(const int* __restrict__ row, int E, int* __restrict__ cnt) {
    int e = blockIdx.x * blockDim.x + threadIdx.x;
    if (e < E) atomicAdd(&cnt[row[e]], 1);
}

__global__ void scan_bsum_kernel(const int* __restrict__ cnt, int* __restrict__ bsum, int N) {
    __shared__ int red[4];
    int i = blockIdx.x * 256 + threadIdx.x;
    int v = (i < N) ? cnt[i] : 0;
#pragma unroll
    for (int m = 32; m >= 1; m >>= 1) v += __shfl_xor(v, m, 64);
    if ((threadIdx.x & 63) == 0) red[threadIdx.x >> 6] = v;
    __syncthreads();
    if (threadIdx.x == 0) bsum[blockIdx.x] = red[0] + red[1] + red[2] + red[3];
}

__global__ void scan_mid_kernel(int* __restrict__ bsum, int nb) {
    __shared__ int s[256];
    int t = threadIdx.x;
    int v = (t < nb) ? bsum[t] : 0;
    s[t] = v;
    __syncthreads();
    for (int o = 1; o < 256; o <<= 1) {
        int u = (t >= o) ? s[t - o] : 0;
        __syncthreads();
        s[t] += u;
        __syncthreads();
    }
    if (t < nb) bsum[t] = s[t] - v;     // exclusive
}

__global__ void scan_offs_kernel(const int* __restrict__ cnt, const int* __restrict__ bsum,
                                 int* __restrict__ offs, float* __restrict__ dis, int N, int E) {
    __shared__ int s[256];
    int b = blockIdx.x, t = threadIdx.x;
    int i = b * 256 + t;
    int v = (i < N) ? cnt[i] : 0;
    s[t] = v;
    __syncthreads();
    for (int o = 1; o < 256; o <<= 1) {
        int u = (t >= o) ? s[t - o] : 0;
        __syncthreads();
        s[t] += u;
        __syncthreads();
    }
    if (i < N) {
        offs[i] = bsum[b] + s[t] - v;
        dis[i]  = rsqrtf((float)v + 1.0f);   // +1 self loop
    }
    if (b == 0 && t == 0) offs[N] = E;
}

__global__ void fill_kernel(const int* __restrict__ row, const int* __restrict__ col, int E,
                            const int* __restrict__ offs, int* __restrict__ fill,
                            const float* __restrict__ dis, int2* __restrict__ cwp) {
    int e = blockIdx.x * blockDim.x + threadIdx.x;
    if (e < E) {
        int r = row[e], c = col[e];
        int pos = offs[r] + atomicAdd(&fill[r], 1);
        int2 q;
        q.x = c;
        q.y = __float_as_int(dis[r] * dis[c]);
        cwp[pos] = q;
    }
}

// ---------------------------------------------------------------------------
// Weight prep: B = [ Wa^T ; Wx^T ] as [2*NPAD][128] hi/lo
// ---------------------------------------------------------------------------
__global__ void wtprep_all_kernel(const float* __restrict__ W1, const float* __restrict__ W2,
                                  const float* __restrict__ W3,
                                  u16* __restrict__ B1h, u16* __restrict__ B1l,
                                  u16* __restrict__ B2h, u16* __restrict__ B2l,
                                  u16* __restrict__ B3h, u16* __restrict__ B3l) {
    int b = blockIdx.x, k = threadIdx.x;   // k: 0..127
    const float* W; u16 *Bh, *Bl; int KSRC, NSRC, NPAD, n;
    if (b < 256)      { W = W1; Bh = B1h; Bl = B1l; KSRC = IN_F;  NSRC = HID_F; NPAD = 128; n = b; }
    else if (b < 512) { W = W2; Bh = B2h; Bl = B2l; KSRC = HID_F; NSRC = HID_F; NPAD = 128; n = b - 256; }
    else              { W = W3; Bh = B3h; Bl = B3l; KSRC = HID_F; NSRC = OUT_F; NPAD = 48;  n = b - 512; }
    int half = (n >= NPAD) ? 1 : 0;
    int cc = n - half * NPAD;
    float v = (cc < NSRC && k < KSRC) ? W[(size_t)(half * KSRC + k) * NSRC + cc] : 0.f;
    u16 h = f2bf(v);
    Bh[(size_t)n * 128 + k] = h;
    Bl[(size_t)n * 128 + k] = f2bf(v - bf2f(h));
}

// ---------------------------------------------------------------------------
// Gather + LayerNorm + ReLU (standalone, NO barrier; wave per node).
// yzin rows [256] bf16: y = cols 0..127 (gathered), z = cols 128..255.
// hout [N][256]: cols 0..127 = hi, 128..255 = lo.
// ---------------------------------------------------------------------------
__global__ __launch_bounds__(256) void gather_ln_kernel(
    const u16* __restrict__ yzin, const int* __restrict__ offs,
    const int2* __restrict__ cwp, const float* __restrict__ dis,
    u16* __restrict__ hout, int N) {
    int node = (blockIdx.x * 256 + threadIdx.x) >> 6;
    int lane = threadIdx.x & 63;
    if (node >= N) return;
    int seg = lane & 15, eg = lane >> 4;

    float a[8];
    if (eg == 0) {     // z + diag-enhanced self loop
        float d = dis[node];
        float sw = 2.f * d * d;
        int4 sv = *(const int4*)(yzin + (size_t)node * 256 + seg * 8);
        int4 zv = *(const int4*)(yzin + (size_t)node * 256 + 128 + seg * 8);
        a[0] = lo2f(zv.x) + sw * lo2f(sv.x); a[1] = hi2f(zv.x) + sw * hi2f(sv.x);
        a[2] = lo2f(zv.y) + sw * lo2f(sv.y); a[3] = hi2f(zv.y) + sw * hi2f(sv.y);
        a[4] = lo2f(zv.z) + sw * lo2f(sv.z); a[5] = hi2f(zv.z) + sw * hi2f(sv.z);
        a[6] = lo2f(zv.w) + sw * lo2f(sv.w); a[7] = hi2f(zv.w) + sw * hi2f(sv.w);
    } else {
#pragma unroll
        for (int j = 0; j < 8; ++j) a[j] = 0.f;
    }

    int s = offs[node], e = offs[node + 1];
#pragma unroll 4
    for (int p0 = s; p0 < e; p0 += 4) {
        int idx = p0 + eg;
        int idc = min(idx, e - 1);
        int2 q = cwp[idc];
        float wt = (idx < e) ? __int_as_float(q.y) : 0.f;
        int4 v = *(const int4*)(yzin + (size_t)q.x * 256 + seg * 8);
        fma8(a, wt, v);
    }

#pragma unroll
    for (int j = 0; j < 8; ++j) {
        a[j] += __shfl_xor(a[j], 16, 64);
        a[j] += __shfl_xor(a[j], 32, 64);
    }
    float s1 = 0.f, s2 = 0.f;
#pragma unroll
    for (int j = 0; j < 8; ++j) { s1 += a[j]; s2 += a[j] * a[j]; }
#pragma unroll
    for (int m = 8; m >= 1; m >>= 1) {
        s1 += __shfl_xor(s1, m, 64);
        s2 += __shfl_xor(s2, m, 64);
    }
    float mu  = s1 * (1.0f / 128);
    float var = s2 * (1.0f / 128) - mu * mu;
    float inv = rsqrtf(var + 1e-5f);
    if (eg == 0) {
        bf16x8 hv, lv;
#pragma unroll
        for (int j = 0; j < 8; ++j) {
            float o = fmaxf((a[j] - mu) * inv, 0.f);
            u16 h = f2bf(o);
            hv[j] = (short)h;
            lv[j] = (short)f2bf(o - bf2f(h));
        }
        *(bf16x8*)(hout + (size_t)node * 256 + seg * 8)       = hv;
        *(bf16x8*)(hout + (size_t)node * 256 + 128 + seg * 8) = lv;
    }
}

// ---------------------------------------------------------------------------
// Shared GEMM core: A tile in sA (hi/lo, 16 rows x 128, stride GSTR), 4 waves.
// ILP-explicit version: hoist A frags (32 VGPR), then issue ALL B loads for
// this wave's tiles up front (up to 32 b128 loads, ~128 VGPR in flight),
// then MFMA + packed 8B stores.  Requires __launch_bounds__(256, 1) on the
// callers so the allocator doesn't squeeze to 36 VGPR (round-10 failure).
// Swapped mfma: lane (g,c16) -> node m0+c16, out-cols base+g*4 (8B store).
// ---------------------------------------------------------------------------
#define GSTR 152

template <int HOUT, int OSTR>
__device__ __forceinline__ void gemm_core(
    const u16* sA0, const u16* sA1,
    const u16* __restrict__ Bh, const u16* __restrict__ Bl,
    u16* __restrict__ yzout, int m0, int tid) {
    int w = tid >> 6, lane = tid & 63;
    int c16 = lane & 15, g = lane >> 4, koff = g * 8;

    constexpr int NTOT = HOUT / 8;           // 16 (HOUT=128) or 6 (HOUT=48)
    constexpr int MAXT = (NTOT + 3) / 4;     // tiles per wave: 4 or 2

    // hoist A fragments (this lane's node row, 4 k-slices, hi+lo)
    bf16x8 ah[4], al[4];
#pragma unroll
    for (int k = 0; k < 4; ++k) {
        ah[k] = *(const bf16x8*)(sA0 + c16 * GSTR + koff + k * 32);
        al[k] = *(const bf16x8*)(sA1 + c16 * GSTR + koff + k * 32);
    }

    // issue ALL B loads first (independent -> deep MLP)
    bf16x8 bh[MAXT][4], bl[MAXT][4];
#pragma unroll
    for (int i = 0; i < MAXT; ++i) {
        int t = w + i * 4;
        if (NTOT == 16 || t < NTOT) {
            const u16* pbh = Bh + (size_t)(t * 16 + c16) * 128 + koff;
            const u16* pbl = Bl + (size_t)(t * 16 + c16) * 128 + koff;
#pragma unroll
            for (int k = 0; k < 4; ++k) {
                bh[i][k] = *(const bf16x8*)(pbh + k * 32);
                bl[i][k] = *(const bf16x8*)(pbl + k * 32);
            }
        }
    }

    // compute + store
#pragma unroll
    for (int i = 0; i < MAXT; ++i) {
        int t = w + i * 4;
        if (NTOT == 16 || t < NTOT) {
            f32x4 acc = (f32x4){0.f, 0.f, 0.f, 0.f};
#pragma unroll
            for (int k = 0; k < 4; ++k) {
                acc = __builtin_amdgcn_mfma_f32_16x16x32_bf16(bh[i][k], ah[k], acc, 0, 0, 0);
                acc = __builtin_amdgcn_mfma_f32_16x16x32_bf16(bh[i][k], al[k], acc, 0, 0, 0);
                acc = __builtin_amdgcn_mfma_f32_16x16x32_bf16(bl[i][k], ah[k], acc, 0, 0, 0);
            }
            int colbase = t * 16 + g * 4;
            if (HOUT == 48 && t >= 3) colbase += 16;   // z half starts at col 64
            bf16x4 o;
            o[0] = (short)f2bf(acc[0]);
            o[1] = (short)f2bf(acc[1]);
            o[2] = (short)f2bf(acc[2]);
            o[3] = (short)f2bf(acc[3]);
            *(bf16x4*)(yzout + (size_t)(m0 + c16) * OSTR + colbase) = o;
        }
    }
}

// ---------------------------------------------------------------------------
// Layer 1: x f32 -> hi/lo LDS -> [y|z] = x @ B1^T -> yz1 [N][256]
// ---------------------------------------------------------------------------
__global__ __launch_bounds__(256, 1) void xgemm_kernel(
    const float* __restrict__ x,
    const u16* __restrict__ Bh, const u16* __restrict__ Bl,
    u16* __restrict__ yzout, int N) {
    __shared__ u16 sA[2][16 * GSTR];
    int tid = threadIdx.x;
    int m0 = blockIdx.x * 16;

#pragma unroll
    for (int i = tid; i < 528; i += 256) {   // 400 data chunks + 128 pad chunks
        int r, c;
        float4 v;
        if (i < 400) {
            r = i / 25; c = (i % 25) * 4;
            v = *(const float4*)(x + (size_t)(m0 + r) * IN_F + c);
        } else {
            int j = i - 400;                     // 0..127
            r = j >> 3; c = 100 + (j & 7) * 4;   // 16 rows x 8 chunks, cols 100..131
            v = (float4){0.f, 0.f, 0.f, 0.f};
        }
        u16 h0 = f2bf(v.x), h1 = f2bf(v.y), h2 = f2bf(v.z), h3 = f2bf(v.w);
        bf16x4 hh = (bf16x4){(short)h0, (short)h1, (short)h2, (short)h3};
        bf16x4 ll = (bf16x4){(short)f2bf(v.x - bf2f(h0)), (short)f2bf(v.y - bf2f(h1)),
                             (short)f2bf(v.z - bf2f(h2)), (short)f2bf(v.w - bf2f(h3))};
        *(bf16x4*)(&sA[0][r * GSTR + c]) = hh;
        *(bf16x4*)(&sA[1][r * GSTR + c]) = ll;
    }
    __syncthreads();
    gemm_core<128, 256>(&sA[0][0], &sA[1][0], Bh, Bl, yzout, m0, tid);
}

// ---------------------------------------------------------------------------
// Mid/last GEMM: h [N][256] (hi|lo) -> LDS -> [y|z] = h @ B^T
// ---------------------------------------------------------------------------
template <int HOUT, int OSTR>
__global__ __launch_bounds__(256, 1) void gemm_mid_kernel(
    const u16* __restrict__ hin,
    const u16* __restrict__ Bh, const u16* __restrict__ Bl,
    u16* __restrict__ yzout, int N) {
    __shared__ u16 sA[2][16 * GSTR];
    int tid = threadIdx.x;
    int m0 = blockIdx.x * 16;

#pragma unroll
    for (int i = tid; i < 512; i += 256) {   // 16 rows x 32 bf16x8 chunks
        int r = i >> 5, cs = i & 31;
        bf16x8 v = *(const bf16x8*)(hin + (size_t)(m0 + r) * 256 + cs * 8);
        if (cs < 16) *(bf16x8*)(&sA[0][r * GSTR + cs * 8]) = v;
        else         *(bf16x8*)(&sA[1][r * GSTR + (cs - 16) * 8]) = v;
    }
    if constexpr (HOUT == 48) {
        if (tid < 128) {   // zero pads: cols [48,64) and [112,128) of 16 rows
            int r = tid >> 3, rem = tid & 7;
            int col = 48 + (rem >> 2) * 64 + (rem & 3) * 4;
            bf16x4 zz = (bf16x4){0, 0, 0, 0};
            *(bf16x4*)(yzout + (size_t)(m0 + r) * OSTR + col) = zz;
        }
    }
    __syncthreads();
    gemm_core<HOUT, OSTR>(&sA[0][0], &sA[1][0], Bh, Bl, yzout, m0, tid);
}

// ---------------------------------------------------------------------------
// Final: out = LN( gather(y3) + self + z3 ).  yz3 [N][128] bf16:
// y cols 0..47 (pad..63), z cols 64..111.  Wave per node; seg=lane&7, eg=lane>>3.
// ---------------------------------------------------------------------------
__global__ __launch_bounds__(256) void final_reduce_kernel(
    const u16* __restrict__ yz, const int* __restrict__ offs,
    const int2* __restrict__ cwp, const float* __restrict__ dis,
    float* __restrict__ out, int N) {
    int node = (blockIdx.x * 256 + threadIdx.x) >> 6;
    int lane = threadIdx.x & 63;
    if (node >= N) return;
    int seg = lane & 7, eg = lane >> 3;

    float a[8];
    if (eg == 0) {
        float d = dis[node];
        float sw = 2.f * d * d;
        int4 sv = *(const int4*)(yz + (size_t)node * 128 + seg * 8);
        int4 zv = *(const int4*)(yz + (size_t)node * 128 + 64 + seg * 8);
        a[0] = lo2f(zv.x) + sw * lo2f(sv.x); a[1] = hi2f(zv.x) + sw * hi2f(sv.x);
        a[2] = lo2f(zv.y) + sw * lo2f(sv.y); a[3] = hi2f(zv.y) + sw * hi2f(sv.y);
        a[4] = lo2f(zv.z) + sw * lo2f(sv.z); a[5] = hi2f(zv.z) + sw * hi2f(sv.z);
        a[6] = lo2f(zv.w) + sw * lo2f(sv.w); a[7] = hi2f(zv.w) + sw * hi2f(sv.w);
    } else {
#pragma unroll
        for (int j = 0; j < 8; ++j) a[j] = 0.f;
    }

    int s = offs[node], e = offs[node + 1];
#pragma unroll 4
    for (int p0 = s; p0 < e; p0 += 8) {
        int idx = p0 + eg;
        int idc = min(idx, e - 1);
        int2 q = cwp[idc];
        float wt = (idx < e) ? __int_as_float(q.y) : 0.f;
        int4 v = *(const int4*)(yz + (size_t)q.x * 128 + seg * 8);
        fma8(a, wt, v);
    }

#pragma unroll
    for (int j = 0; j < 8; ++j) {
        a[j] += __shfl_xor(a[j], 8, 64);
        a[j] += __shfl_xor(a[j], 16, 64);
        a[j] += __shfl_xor(a[j], 32, 64);
    }
    float s1 = 0.f, s2 = 0.f;
#pragma unroll
    for (int j = 0; j < 8; ++j) {
        int col = seg * 8 + j;
        if (col < OUT_F) { s1 += a[j]; s2 += a[j] * a[j]; }
    }
#pragma unroll
    for (int m = 4; m >= 1; m >>= 1) {
        s1 += __shfl_xor(s1, m, 64);
        s2 += __shfl_xor(s2, m, 64);
    }
    float mu  = s1 * (1.0f / OUT_F);
    float var = s2 * (1.0f / OUT_F) - mu * mu;
    float inv = rsqrtf(var + 1e-5f);

    if (eg == 0) {
#pragma unroll
        for (int j = 0; j < 8; ++j) {
            int col = seg * 8 + j;
            if (col < OUT_F)
                out[(size_t)node * OUT_F + col] = (a[j] - mu) * inv;
        }
    }
}

// ---------------------------------------------------------------------------
extern "C" void kernel_launch(void* const* d_in, const int* in_sizes, int n_in,
                              void* d_out, int out_size, void* d_ws, size_t ws_size,
                              hipStream_t stream) {
    const float* x  = (const float*)d_in[0];
    const int*   ei = (const int*)d_in[1];
    const float* W1 = (const float*)d_in[2];
    const float* W2 = (const float*)d_in[3];
    const float* W3 = (const float*)d_in[4];
    float* out = (float*)d_out;

    const int N = in_sizes[0] / IN_F;   // 50000
    const int E = in_sizes[1] / 2;      // 800000
    const int* erow = ei;
    const int* ecol = ei + E;

    char* p = (char*)d_ws;
    auto alloc = [&](size_t bytes) -> void* {
        void* r = (void*)p;
        p += (bytes + 255) & ~(size_t)255;
        return r;
    };
    int*   cnt  = (int*)  alloc((size_t)N * 4);
    int*   offs = (int*)  alloc((size_t)(N + 1) * 4);
    int*   fill = (int*)  alloc((size_t)N * 4);
    float* dis  = (float*)alloc((size_t)N * 4);
    int*   bsum = (int*)  alloc((size_t)256 * 4);
    int2*  cwp  = (int2*) alloc((size_t)(E + 16) * 8);
    u16*   yzA  = (u16*)  alloc((size_t)N * 256 * 2);   // 25.6 MB
    u16*   yzB  = (u16*)  alloc((size_t)N * 256 * 2);
    u16*   yzC  = (u16*)  alloc((size_t)N * 128 * 2);
    u16*   hbuf = (u16*)  alloc((size_t)N * 256 * 2);   // h hi|lo
    u16*   B1h  = (u16*)  alloc((size_t)256 * 128 * 2);
    u16*   B1l  = (u16*)  alloc((size_t)256 * 128 * 2);
    u16*   B2h  = (u16*)  alloc((size_t)256 * 128 * 2);
    u16*   B2l  = (u16*)  alloc((size_t)256 * 128 * 2);
    u16*   B3h  = (u16*)  alloc((size_t)96 * 128 * 2);
    u16*   B3l  = (u16*)  alloc((size_t)96 * 128 * 2);

    hipMemsetAsync(cnt,  0, (size_t)N * 4, stream);
    hipMemsetAsync(fill, 0, (size_t)N * 4, stream);

    const int egrid = (E + 255) / 256;       // 3125
    const int nb    = (N + 255) / 256;       // 196

    count_kernel<<<egrid, 256, 0, stream>>>(erow, E, cnt);
    scan_bsum_kernel<<<nb, 256, 0, stream>>>(cnt, bsum, N);
    scan_mid_kernel<<<1, 256, 0, stream>>>(bsum, nb);
    scan_offs_kernel<<<nb, 256, 0, stream>>>(cnt, bsum, offs, dis, N, E);
    fill_kernel<<<egrid, 256, 0, stream>>>(erow, ecol, E, offs, fill, dis, cwp);

    wtprep_all_kernel<<<608, 128, 0, stream>>>(W1, W2, W3, B1h, B1l, B2h, B2l, B3h, B3l);

    const int gblocks = N / 16;               // 3125 (256-thr blocks)
    const int wblocks = (N * 64 + 255) / 256; // 12500 (wave per node)

    // layer 1: x -> yz1
    xgemm_kernel<<<gblocks, 256, 0, stream>>>(x, B1h, B1l, yzA, N);
    // layer 2
    gather_ln_kernel<<<wblocks, 256, 0, stream>>>(yzA, offs, cwp, dis, hbuf, N);
    gemm_mid_kernel<128, 256><<<gblocks, 256, 0, stream>>>(hbuf, B2h, B2l, yzB, N);
    // layer 3
    gather_ln_kernel<<<wblocks, 256, 0, stream>>>(yzB, offs, cwp, dis, hbuf, N);
    gemm_mid_kernel<48, 128><<<gblocks, 256, 0, stream>>>(hbuf, B3h, B3l, yzC, N);
    // final
    final_reduce_kernel<<<wblocks, 256, 0, stream>>>(yzC, offs, cwp, dis, out, N);
}

// Round 12
// 301.244 us; speedup vs baseline: 1.1000x; 1.1000x over previous
//
#include <hip/hip_runtime.h>

#define IN_F   100
#define HID_F  128
#define OUT_F  47
#define ROWS   128   // rows per GEMM block (8 A-tiles)

typedef short bf16x8 __attribute__((ext_vector_type(8)));
typedef short bf16x4 __attribute__((ext_vector_type(4)));
typedef float f32x4  __attribute__((ext_vector_type(4)));
typedef unsigned short u16;
typedef unsigned int   u32;

__device__ __forceinline__ u16 f2bf(float f) {
    u32 u = __float_as_uint(f);
    u += 0x7FFFu + ((u >> 16) & 1u);           // RNE
    return (u16)(u >> 16);
}
__device__ __forceinline__ float bf2f(u16 b) { return __uint_as_float(((u32)b) << 16); }
__device__ __forceinline__ float lo2f(u32 v) { return __uint_as_float(v << 16); }
__device__ __forceinline__ float hi2f(u32 v) { return __uint_as_float(v & 0xFFFF0000u); }

__device__ __forceinline__ void fma8(float* a, float wt, int4 v) {
    a[0] += wt * lo2f(v.x); a[1] += wt * hi2f(v.x);
    a[2] += wt * lo2f(v.y); a[3] += wt * hi2f(v.y);
    a[4] += wt * lo2f(v.z); a[5] += wt * hi2f(v.z);
    a[6] += wt * lo2f(v.w); a[7] += wt * hi2f(v.w);
}

// ---------------------------------------------------------------------------
// CSR build
// ---------------------------------------------------------------------------
__global__ void count_kernel(const int* __restrict__ row, int E, int* __restrict__ cnt) {
    int e = blockIdx.x * blockDim.x + threadIdx.x;
    if (e < E) atomicAdd(&cnt[row[e]], 1);
}

__global__ void scan_bsum_kernel(const int* __restrict__ cnt, int* __restrict__ bsum, int N) {
    __shared__ int red[4];
    int i = blockIdx.x * 256 + threadIdx.x;
    int v = (i < N) ? cnt[i] : 0;
#pragma unroll
    for (int m = 32; m >= 1; m >>= 1) v += __shfl_xor(v, m, 64);
    if ((threadIdx.x & 63) == 0) red[threadIdx.x >> 6] = v;
    __syncthreads();
    if (threadIdx.x == 0) bsum[blockIdx.x] = red[0] + red[1] + red[2] + red[3];
}

__global__ void scan_mid_kernel(int* __restrict__ bsum, int nb) {
    __shared__ int s[256];
    int t = threadIdx.x;
    int v = (t < nb) ? bsum[t] : 0;
    s[t] = v;
    __syncthreads();
    for (int o = 1; o < 256; o <<= 1) {
        int u = (t >= o) ? s[t - o] : 0;
        __syncthreads();
        s[t] += u;
        __syncthreads();
    }
    if (t < nb) bsum[t] = s[t] - v;     // exclusive
}

__global__ void scan_offs_kernel(const int* __restrict__ cnt, const int* __restrict__ bsum,
                                 int* __restrict__ offs, float* __restrict__ dis, int N, int E) {
    __shared__ int s[256];
    int b = blockIdx.x, t = threadIdx.x;
    int i = b * 256 + t;
    int v = (i < N) ? cnt[i] : 0;
    s[t] = v;
    __syncthreads();
    for (int o = 1; o < 256; o <<= 1) {
        int u = (t >= o) ? s[t - o] : 0;
        __syncthreads();
        s[t] += u;
        __syncthreads();
    }
    if (i < N) {
        offs[i] = bsum[b] + s[t] - v;
        dis[i]  = rsqrtf((float)v + 1.0f);   // +1 self loop
    }
    if (b == 0 && t == 0) offs[N] = E;
}

__global__ void fill_kernel(const int* __restrict__ row, const int* __restrict__ col, int E,
                            const int* __restrict__ offs, int* __restrict__ fill,
                            const float* __restrict__ dis, int2* __restrict__ cwp) {
    int e = blockIdx.x * blockDim.x + threadIdx.x;
    if (e < E) {
        int r = row[e], c = col[e];
        int pos = offs[r] + atomicAdd(&fill[r], 1);
        int2 q;
        q.x = c;
        q.y = __float_as_int(dis[r] * dis[c]);
        cwp[pos] = q;
    }
}

// ---------------------------------------------------------------------------
// Weight prep: B = [ Wa^T ; Wx^T ] as [2*NPAD][128] hi/lo
// ---------------------------------------------------------------------------
__global__ void wtprep_all_kernel(const float* __restrict__ W1, const float* __restrict__ W2,
                                  const float* __restrict__ W3,
                                  u16* __restrict__ B1h, u16* __restrict__ B1l,
                                  u16* __restrict__ B2h, u16* __restrict__ B2l,
                                  u16* __restrict__ B3h, u16* __restrict__ B3l) {
    int b = blockIdx.x, k = threadIdx.x;   // k: 0..127
    const float* W; u16 *Bh, *Bl; int KSRC, NSRC, NPAD, n;
    if (b < 256)      { W = W1; Bh = B1h; Bl = B1l; KSRC = IN_F;  NSRC = HID_F; NPAD = 128; n = b; }
    else if (b < 512) { W = W2; Bh = B2h; Bl = B2l; KSRC = HID_F; NSRC = HID_F; NPAD = 128; n = b - 256; }
    else              { W = W3; Bh = B3h; Bl = B3l; KSRC = HID_F; NSRC = OUT_F; NPAD = 48;  n = b - 512; }
    int half = (n >= NPAD) ? 1 : 0;
    int cc = n - half * NPAD;
    float v = (cc < NSRC && k < KSRC) ? W[(size_t)(half * KSRC + k) * NSRC + cc] : 0.f;
    u16 h = f2bf(v);
    Bh[(size_t)n * 128 + k] = h;
    Bl[(size_t)n * 128 + k] = f2bf(v - bf2f(h));
}

// ---------------------------------------------------------------------------
// Gather + LayerNorm + ReLU (standalone, NO barrier; wave per node).
// yzin rows [256] bf16: y = cols 0..127 (gathered), z = cols 128..255.
// hout [N][256]: cols 0..127 = hi, 128..255 = lo.
// ---------------------------------------------------------------------------
__global__ __launch_bounds__(256) void gather_ln_kernel(
    const u16* __restrict__ yzin, const int* __restrict__ offs,
    const int2* __restrict__ cwp, const float* __restrict__ dis,
    u16* __restrict__ hout, int N) {
    int node = (blockIdx.x * 256 + threadIdx.x) >> 6;
    int lane = threadIdx.x & 63;
    if (node >= N) return;
    int seg = lane & 15, eg = lane >> 4;

    float a[8];
    if (eg == 0) {     // z + diag-enhanced self loop
        float d = dis[node];
        float sw = 2.f * d * d;
        int4 sv = *(const int4*)(yzin + (size_t)node * 256 + seg * 8);
        int4 zv = *(const int4*)(yzin + (size_t)node * 256 + 128 + seg * 8);
        a[0] = lo2f(zv.x) + sw * lo2f(sv.x); a[1] = hi2f(zv.x) + sw * hi2f(sv.x);
        a[2] = lo2f(zv.y) + sw * lo2f(sv.y); a[3] = hi2f(zv.y) + sw * hi2f(sv.y);
        a[4] = lo2f(zv.z) + sw * lo2f(sv.z); a[5] = hi2f(zv.z) + sw * hi2f(sv.z);
        a[6] = lo2f(zv.w) + sw * lo2f(sv.w); a[7] = hi2f(zv.w) + sw * hi2f(sv.w);
    } else {
#pragma unroll
        for (int j = 0; j < 8; ++j) a[j] = 0.f;
    }

    int s = offs[node], e = offs[node + 1];
#pragma unroll 4
    for (int p0 = s; p0 < e; p0 += 4) {
        int idx = p0 + eg;
        int idc = min(idx, e - 1);
        int2 q = cwp[idc];
        float wt = (idx < e) ? __int_as_float(q.y) : 0.f;
        int4 v = *(const int4*)(yzin + (size_t)q.x * 256 + seg * 8);
        fma8(a, wt, v);
    }

#pragma unroll
    for (int j = 0; j < 8; ++j) {
        a[j] += __shfl_xor(a[j], 16, 64);
        a[j] += __shfl_xor(a[j], 32, 64);
    }
    float s1 = 0.f, s2 = 0.f;
#pragma unroll
    for (int j = 0; j < 8; ++j) { s1 += a[j]; s2 += a[j] * a[j]; }
#pragma unroll
    for (int m = 8; m >= 1; m >>= 1) {
        s1 += __shfl_xor(s1, m, 64);
        s2 += __shfl_xor(s2, m, 64);
    }
    float mu  = s1 * (1.0f / 128);
    float var = s2 * (1.0f / 128) - mu * mu;
    float inv = rsqrtf(var + 1e-5f);
    if (eg == 0) {
        bf16x8 hv, lv;
#pragma unroll
        for (int j = 0; j < 8; ++j) {
            float o = fmaxf((a[j] - mu) * inv, 0.f);
            u16 h = f2bf(o);
            hv[j] = (short)h;
            lv[j] = (short)f2bf(o - bf2f(h));
        }
        *(bf16x8*)(hout + (size_t)node * 256 + seg * 8)       = hv;
        *(bf16x8*)(hout + (size_t)node * 256 + 128 + seg * 8) = lv;
    }
}

// ---------------------------------------------------------------------------
// B-register-resident GEMM (mid/last): NO LDS, NO barrier.
// Block = WAVES waves, ROWS rows (ROWS/16 A-tiles).  Wave w owns TPW B-tiles
// (fragments loaded ONCE into ~32 VGPR per tile), then loops over A-tiles
// loading A-frags straight from global (coalesced b128) and issuing MFMA.
// Swapped mfma: lane (g,c16) -> node row+c16... node = m0+t*16+c16,
// out-cols colbase+g*4+reg -> packed 8B store.
// hin rows [256] u16: hi = cols 0..127, lo = 128..255.
// ---------------------------------------------------------------------------
template <int HOUT, int OSTR, int WAVES>
__global__ __launch_bounds__(WAVES * 64, 1) void gemm_breg_kernel(
    const u16* __restrict__ hin,
    const u16* __restrict__ Bh, const u16* __restrict__ Bl,
    u16* __restrict__ yzout, int N) {
    constexpr int NTOT = HOUT / 8;           // 16 or 6 B-tiles
    constexpr int TPW  = NTOT / WAVES;       // 2 (HOUT=128) or 1 (HOUT=48)
    int tid = threadIdx.x;
    int w = tid >> 6, lane = tid & 63;
    int c16 = lane & 15, g = lane >> 4, koff = g * 8;
    int m0 = blockIdx.x * ROWS;
    int tmax = min(ROWS, N - m0) >> 4;

    if constexpr (HOUT == 48) {
        // zero pads for this block's rows: cols [48,64) and [112,128)
        for (int i = tid; i < ROWS * 8; i += WAVES * 64) {
            int r = i >> 3, rem = i & 7;
            if (m0 + r < N) {
                int col = 48 + (rem >> 2) * 64 + (rem & 3) * 4;
                bf16x4 zz = (bf16x4){0, 0, 0, 0};
                *(bf16x4*)(yzout + (size_t)(m0 + r) * OSTR + col) = zz;
            }
        }
    }

    // B fragments: loaded once, resident for the whole kernel
    bf16x8 bh[TPW][4], bl[TPW][4];
#pragma unroll
    for (int i = 0; i < TPW; ++i) {
        int t = w * TPW + i;
        const u16* pbh = Bh + (size_t)(t * 16 + c16) * 128 + koff;
        const u16* pbl = Bl + (size_t)(t * 16 + c16) * 128 + koff;
#pragma unroll
        for (int k = 0; k < 4; ++k) {
            bh[i][k] = *(const bf16x8*)(pbh + k * 32);
            bl[i][k] = *(const bf16x8*)(pbl + k * 32);
        }
    }

#pragma unroll 2
    for (int t = 0; t < tmax; ++t) {
        int row = m0 + t * 16 + c16;
        const u16* pa = hin + (size_t)row * 256 + koff;
        bf16x8 ah[4], al[4];
#pragma unroll
        for (int k = 0; k < 4; ++k) {
            ah[k] = *(const bf16x8*)(pa + k * 32);
            al[k] = *(const bf16x8*)(pa + 128 + k * 32);
        }
#pragma unroll
        for (int i = 0; i < TPW; ++i) {
            int tt = w * TPW + i;
            f32x4 acc = (f32x4){0.f, 0.f, 0.f, 0.f};
#pragma unroll
            for (int k = 0; k < 4; ++k) {
                acc = __builtin_amdgcn_mfma_f32_16x16x32_bf16(bh[i][k], ah[k], acc, 0, 0, 0);
                acc = __builtin_amdgcn_mfma_f32_16x16x32_bf16(bh[i][k], al[k], acc, 0, 0, 0);
                acc = __builtin_amdgcn_mfma_f32_16x16x32_bf16(bl[i][k], ah[k], acc, 0, 0, 0);
            }
            int colbase = tt * 16 + g * 4;
            if (HOUT == 48 && tt >= 3) colbase += 16;   // z half at col 64
            bf16x4 o;
            o[0] = (short)f2bf(acc[0]);
            o[1] = (short)f2bf(acc[1]);
            o[2] = (short)f2bf(acc[2]);
            o[3] = (short)f2bf(acc[3]);
            *(bf16x4*)(yzout + (size_t)row * OSTR + colbase) = o;
        }
    }
}

// ---------------------------------------------------------------------------
// Layer-1 GEMM: same structure; A-frags converted from f32 x in registers.
// ---------------------------------------------------------------------------
__global__ __launch_bounds__(512, 1) void xgemm_breg_kernel(
    const float* __restrict__ x,
    const u16* __restrict__ Bh, const u16* __restrict__ Bl,
    u16* __restrict__ yzout, int N) {
    int tid = threadIdx.x;
    int w = tid >> 6, lane = tid & 63;
    int c16 = lane & 15, g = lane >> 4, koff = g * 8;
    int m0 = blockIdx.x * ROWS;
    int tmax = min(ROWS, N - m0) >> 4;

    bf16x8 bh[2][4], bl[2][4];
#pragma unroll
    for (int i = 0; i < 2; ++i) {
        int t = w * 2 + i;
        const u16* pbh = Bh + (size_t)(t * 16 + c16) * 128 + koff;
        const u16* pbl = Bl + (size_t)(t * 16 + c16) * 128 + koff;
#pragma unroll
        for (int k = 0; k < 4; ++k) {
            bh[i][k] = *(const bf16x8*)(pbh + k * 32);
            bl[i][k] = *(const bf16x8*)(pbl + k * 32);
        }
    }

#pragma unroll 2
    for (int t = 0; t < tmax; ++t) {
        int row = m0 + t * 16 + c16;
        const float* px = x + (size_t)row * IN_F;
        bf16x8 ah[4], al[4];
#pragma unroll
        for (int k = 0; k < 4; ++k) {
            int c0 = koff + k * 32;
            float4 v0 = (c0 < IN_F)     ? *(const float4*)(px + c0)     : (float4){0.f, 0.f, 0.f, 0.f};
            float4 v1 = (c0 + 4 < IN_F) ? *(const float4*)(px + c0 + 4) : (float4){0.f, 0.f, 0.f, 0.f};
            float f[8] = {v0.x, v0.y, v0.z, v0.w, v1.x, v1.y, v1.z, v1.w};
#pragma unroll
            for (int j = 0; j < 8; ++j) {
                u16 h = f2bf(f[j]);
                ah[k][j] = (short)h;
                al[k][j] = (short)f2bf(f[j] - bf2f(h));
            }
        }
#pragma unroll
        for (int i = 0; i < 2; ++i) {
            int tt = w * 2 + i;
            f32x4 acc = (f32x4){0.f, 0.f, 0.f, 0.f};
#pragma unroll
            for (int k = 0; k < 4; ++k) {
                acc = __builtin_amdgcn_mfma_f32_16x16x32_bf16(bh[i][k], ah[k], acc, 0, 0, 0);
                acc = __builtin_amdgcn_mfma_f32_16x16x32_bf16(bh[i][k], al[k], acc, 0, 0, 0);
                acc = __builtin_amdgcn_mfma_f32_16x16x32_bf16(bl[i][k], ah[k], acc, 0, 0, 0);
            }
            int colbase = tt * 16 + g * 4;
            bf16x4 o;
            o[0] = (short)f2bf(acc[0]);
            o[1] = (short)f2bf(acc[1]);
            o[2] = (short)f2bf(acc[2]);
            o[3] = (short)f2bf(acc[3]);
            *(bf16x4*)(yzout + (size_t)row * 256 + colbase) = o;
        }
    }
}

// ---------------------------------------------------------------------------
// Final: out = LN( gather(y3) + self + z3 ).  yz3 [N][128] bf16:
// y cols 0..47 (pad..63), z cols 64..111.  Wave per node; seg=lane&7, eg=lane>>3.
// ---------------------------------------------------------------------------
__global__ __launch_bounds__(256) void final_reduce_kernel(
    const u16* __restrict__ yz, const int* __restrict__ offs,
    const int2* __restrict__ cwp, const float* __restrict__ dis,
    float* __restrict__ out, int N) {
    int node = (blockIdx.x * 256 + threadIdx.x) >> 6;
    int lane = threadIdx.x & 63;
    if (node >= N) return;
    int seg = lane & 7, eg = lane >> 3;

    float a[8];
    if (eg == 0) {
        float d = dis[node];
        float sw = 2.f * d * d;
        int4 sv = *(const int4*)(yz + (size_t)node * 128 + seg * 8);
        int4 zv = *(const int4*)(yz + (size_t)node * 128 + 64 + seg * 8);
        a[0] = lo2f(zv.x) + sw * lo2f(sv.x); a[1] = hi2f(zv.x) + sw * hi2f(sv.x);
        a[2] = lo2f(zv.y) + sw * lo2f(sv.y); a[3] = hi2f(zv.y) + sw * hi2f(sv.y);
        a[4] = lo2f(zv.z) + sw * lo2f(sv.z); a[5] = hi2f(zv.z) + sw * hi2f(sv.z);
        a[6] = lo2f(zv.w) + sw * lo2f(sv.w); a[7] = hi2f(zv.w) + sw * hi2f(sv.w);
    } else {
#pragma unroll
        for (int j = 0; j < 8; ++j) a[j] = 0.f;
    }

    int s = offs[node], e = offs[node + 1];
#pragma unroll 4
    for (int p0 = s; p0 < e; p0 += 8) {
        int idx = p0 + eg;
        int idc = min(idx, e - 1);
        int2 q = cwp[idc];
        float wt = (idx < e) ? __int_as_float(q.y) : 0.f;
        int4 v = *(const int4*)(yz + (size_t)q.x * 128 + seg * 8);
        fma8(a, wt, v);
    }

#pragma unroll
    for (int j = 0; j < 8; ++j) {
        a[j] += __shfl_xor(a[j], 8, 64);
        a[j] += __shfl_xor(a[j], 16, 64);
        a[j] += __shfl_xor(a[j], 32, 64);
    }
    float s1 = 0.f, s2 = 0.f;
#pragma unroll
    for (int j = 0; j < 8; ++j) {
        int col = seg * 8 + j;
        if (col < OUT_F) { s1 += a[j]; s2 += a[j] * a[j]; }
    }
#pragma unroll
    for (int m = 4; m >= 1; m >>= 1) {
        s1 += __shfl_xor(s1, m, 64);
        s2 += __shfl_xor(s2, m, 64);
    }
    float mu  = s1 * (1.0f / OUT_F);
    float var = s2 * (1.0f / OUT_F) - mu * mu;
    float inv = rsqrtf(var + 1e-5f);

    if (eg == 0) {
#pragma unroll
        for (int j = 0; j < 8; ++j) {
            int col = seg * 8 + j;
            if (col < OUT_F)
                out[(size_t)node * OUT_F + col] = (a[j] - mu) * inv;
        }
    }
}

// ---------------------------------------------------------------------------
extern "C" void kernel_launch(void* const* d_in, const int* in_sizes, int n_in,
                              void* d_out, int out_size, void* d_ws, size_t ws_size,
                              hipStream_t stream) {
    const float* x  = (const float*)d_in[0];
    const int*   ei = (const int*)d_in[1];
    const float* W1 = (const float*)d_in[2];
    const float* W2 = (const float*)d_in[3];
    const float* W3 = (const float*)d_in[4];
    float* out = (float*)d_out;

    const int N = in_sizes[0] / IN_F;   // 50000
    const int E = in_sizes[1] / 2;      // 800000
    const int* erow = ei;
    const int* ecol = ei + E;

    char* p = (char*)d_ws;
    auto alloc = [&](size_t bytes) -> void* {
        void* r = (void*)p;
        p += (bytes + 255) & ~(size_t)255;
        return r;
    };
    int*   cnt  = (int*)  alloc((size_t)N * 4);
    int*   offs = (int*)  alloc((size_t)(N + 1) * 4);
    int*   fill = (int*)  alloc((size_t)N * 4);
    float* dis  = (float*)alloc((size_t)N * 4);
    int*   bsum = (int*)  alloc((size_t)256 * 4);
    int2*  cwp  = (int2*) alloc((size_t)(E + 16) * 8);
    u16*   yzA  = (u16*)  alloc((size_t)N * 256 * 2);   // 25.6 MB
    u16*   yzB  = (u16*)  alloc((size_t)N * 256 * 2);
    u16*   yzC  = (u16*)  alloc((size_t)N * 128 * 2);
    u16*   hbuf = (u16*)  alloc((size_t)N * 256 * 2);   // h hi|lo
    u16*   B1h  = (u16*)  alloc((size_t)256 * 128 * 2);
    u16*   B1l  = (u16*)  alloc((size_t)256 * 128 * 2);
    u16*   B2h  = (u16*)  alloc((size_t)256 * 128 * 2);
    u16*   B2l  = (u16*)  alloc((size_t)256 * 128 * 2);
    u16*   B3h  = (u16*)  alloc((size_t)96 * 128 * 2);
    u16*   B3l  = (u16*)  alloc((size_t)96 * 128 * 2);

    hipMemsetAsync(cnt,  0, (size_t)N * 4, stream);
    hipMemsetAsync(fill, 0, (size_t)N * 4, stream);

    const int egrid = (E + 255) / 256;       // 3125
    const int nb    = (N + 255) / 256;       // 196

    count_kernel<<<egrid, 256, 0, stream>>>(erow, E, cnt);
    scan_bsum_kernel<<<nb, 256, 0, stream>>>(cnt, bsum, N);
    scan_mid_kernel<<<1, 256, 0, stream>>>(bsum, nb);
    scan_offs_kernel<<<nb, 256, 0, stream>>>(cnt, bsum, offs, dis, N, E);
    fill_kernel<<<egrid, 256, 0, stream>>>(erow, ecol, E, offs, fill, dis, cwp);

    wtprep_all_kernel<<<608, 128, 0, stream>>>(W1, W2, W3, B1h, B1l, B2h, B2l, B3h, B3l);

    const int gblocks = (N + ROWS - 1) / ROWS;   // 391
    const int wblocks = (N * 64 + 255) / 256;    // 12500 (wave per node)

    // layer 1: x -> yz1
    xgemm_breg_kernel<<<gblocks, 512, 0, stream>>>(x, B1h, B1l, yzA, N);
    // layer 2
    gather_ln_kernel<<<wblocks, 256, 0, stream>>>(yzA, offs, cwp, dis, hbuf, N);
    gemm_breg_kernel<128, 256, 8><<<gblocks, 512, 0, stream>>>(hbuf, B2h, B2l, yzB, N);
    // layer 3
    gather_ln_kernel<<<wblocks, 256, 0, stream>>>(yzB, offs, cwp, dis, hbuf, N);
    gemm_breg_kernel<48, 128, 6><<<gblocks, 384, 0, stream>>>(hbuf, B3h, B3l, yzC, N);
    // final
    final_reduce_kernel<<<wblocks, 256, 0, stream>>>(yzC, offs, cwp, dis, out, N);
}

// Round 13
// 297.791 us; speedup vs baseline: 1.1128x; 1.0116x over previous
//
#include <hip/hip_runtime.h>

#define IN_F   100
#define HID_F  128
#define OUT_F  47
#define ROWS   128   // rows per GEMM block (8 A-tiles)

typedef short bf16x8 __attribute__((ext_vector_type(8)));
typedef short bf16x4 __attribute__((ext_vector_type(4)));
typedef float f32x4  __attribute__((ext_vector_type(4)));
typedef float f32x2  __attribute__((ext_vector_type(2)));
typedef unsigned short u16;
typedef unsigned int   u32;

__device__ __forceinline__ u16 f2bf(float f) {
    u32 u = __float_as_uint(f);
    u += 0x7FFFu + ((u >> 16) & 1u);           // RNE
    return (u16)(u >> 16);
}
__device__ __forceinline__ float bf2f(u16 b) { return __uint_as_float(((u32)b) << 16); }
__device__ __forceinline__ float lo2f(u32 v) { return __uint_as_float(v << 16); }
__device__ __forceinline__ float hi2f(u32 v) { return __uint_as_float(v & 0xFFFF0000u); }

// unpack one dword (2 bf16) -> f32x2 {even col, odd col}
__device__ __forceinline__ f32x2 unpk(u32 v) {
    f32x2 r;
    r.x = __uint_as_float(v << 16);
    r.y = __uint_as_float(v & 0xFFFF0000u);
    return r;
}

// ---------------------------------------------------------------------------
// CSR build
// ---------------------------------------------------------------------------
__global__ void count_kernel(const int* __restrict__ row, int E, int* __restrict__ cnt) {
    int e = blockIdx.x * blockDim.x + threadIdx.x;
    if (e < E) atomicAdd(&cnt[row[e]], 1);
}

__global__ void scan_bsum_kernel(const int* __restrict__ cnt, int* __restrict__ bsum, int N) {
    __shared__ int red[4];
    int i = blockIdx.x * 256 + threadIdx.x;
    int v = (i < N) ? cnt[i] : 0;
#pragma unroll
    for (int m = 32; m >= 1; m >>= 1) v += __shfl_xor(v, m, 64);
    if ((threadIdx.x & 63) == 0) red[threadIdx.x >> 6] = v;
    __syncthreads();
    if (threadIdx.x == 0) bsum[blockIdx.x] = red[0] + red[1] + red[2] + red[3];
}

__global__ void scan_mid_kernel(int* __restrict__ bsum, int nb) {
    __shared__ int s[256];
    int t = threadIdx.x;
    int v = (t < nb) ? bsum[t] : 0;
    s[t] = v;
    __syncthreads();
    for (int o = 1; o < 256; o <<= 1) {
        int u = (t >= o) ? s[t - o] : 0;
        __syncthreads();
        s[t] += u;
        __syncthreads();
    }
    if (t < nb) bsum[t] = s[t] - v;     // exclusive
}

__global__ void scan_offs_kernel(const int* __restrict__ cnt, const int* __restrict__ bsum,
                                 int* __restrict__ offs, float* __restrict__ dis, int N, int E) {
    __shared__ int s[256];
    int b = blockIdx.x, t = threadIdx.x;
    int i = b * 256 + t;
    int v = (i < N) ? cnt[i] : 0;
    s[t] = v;
    __syncthreads();
    for (int o = 1; o < 256; o <<= 1) {
        int u = (t >= o) ? s[t - o] : 0;
        __syncthreads();
        s[t] += u;
        __syncthreads();
    }
    if (i < N) {
        offs[i] = bsum[b] + s[t] - v;
        dis[i]  = rsqrtf((float)v + 1.0f);   // +1 self loop
    }
    if (b == 0 && t == 0) offs[N] = E;
}

// XCD-sliced fill: block (bid&7) handles only dst in node-slice (bid&7).
// Slice's CSR region (~800KB) stays resident in that XCD's L2, so the
// scattered 8B writes merge instead of thrashing lines across 8 XCDs.
__global__ void fill_slice_kernel(const int* __restrict__ row, const int* __restrict__ col,
                                  int E, const int* __restrict__ offs, int* __restrict__ fill,
                                  const float* __restrict__ dis, int2* __restrict__ cwp,
                                  int N) {
    int slice = blockIdx.x & 7;
    int e = (blockIdx.x >> 3) * 256 + threadIdx.x;
    if (e >= E) return;
    int srange = (N + 7) >> 3;
    int lo = slice * srange, hi = min(lo + srange, N);
    int r = row[e];
    if (r < lo || r >= hi) return;
    int c = col[e];
    int pos = offs[r] + atomicAdd(&fill[r], 1);
    int2 q;
    q.x = c;
    q.y = __float_as_int(dis[r] * dis[c]);
    cwp[pos] = q;
}

// ---------------------------------------------------------------------------
// Weight prep: B = [ Wa^T ; Wx^T ] as [2*NPAD][128] hi/lo
// ---------------------------------------------------------------------------
__global__ void wtprep_all_kernel(const float* __restrict__ W1, const float* __restrict__ W2,
                                  const float* __restrict__ W3,
                                  u16* __restrict__ B1h, u16* __restrict__ B1l,
                                  u16* __restrict__ B2h, u16* __restrict__ B2l,
                                  u16* __restrict__ B3h, u16* __restrict__ B3l) {
    int b = blockIdx.x, k = threadIdx.x;   // k: 0..127
    const float* W; u16 *Bh, *Bl; int KSRC, NSRC, NPAD, n;
    if (b < 256)      { W = W1; Bh = B1h; Bl = B1l; KSRC = IN_F;  NSRC = HID_F; NPAD = 128; n = b; }
    else if (b < 512) { W = W2; Bh = B2h; Bl = B2l; KSRC = HID_F; NSRC = HID_F; NPAD = 128; n = b - 256; }
    else              { W = W3; Bh = B3h; Bl = B3l; KSRC = HID_F; NSRC = OUT_F; NPAD = 48;  n = b - 512; }
    int half = (n >= NPAD) ? 1 : 0;
    int cc = n - half * NPAD;
    float v = (cc < NSRC && k < KSRC) ? W[(size_t)(half * KSRC + k) * NSRC + cc] : 0.f;
    u16 h = f2bf(v);
    Bh[(size_t)n * 128 + k] = h;
    Bl[(size_t)n * 128 + k] = f2bf(v - bf2f(h));
}

// ---------------------------------------------------------------------------
// Gather + LayerNorm + ReLU (standalone, NO barrier; wave per node).
// yzin rows [256] bf16: y = cols 0..127 (gathered), z = cols 128..255.
// hout [N][256]: cols 0..127 = hi, 128..255 = lo.
// Accumulators are f32x2 -> v_pk_fma_f32 (2 FMA/instr).
// ---------------------------------------------------------------------------
__global__ __launch_bounds__(256) void gather_ln_kernel(
    const u16* __restrict__ yzin, const int* __restrict__ offs,
    const int2* __restrict__ cwp, const float* __restrict__ dis,
    u16* __restrict__ hout, int N) {
    int node = (blockIdx.x * 256 + threadIdx.x) >> 6;
    int lane = threadIdx.x & 63;
    if (node >= N) return;
    int seg = lane & 15, eg = lane >> 4;

    f32x2 a[4];
    if (eg == 0) {     // z + diag-enhanced self loop
        float d = dis[node];
        float sw = 2.f * d * d;
        f32x2 sw2 = {sw, sw};
        int4 sv = *(const int4*)(yzin + (size_t)node * 256 + seg * 8);
        int4 zv = *(const int4*)(yzin + (size_t)node * 256 + 128 + seg * 8);
        a[0] = unpk((u32)zv.x) + sw2 * unpk((u32)sv.x);
        a[1] = unpk((u32)zv.y) + sw2 * unpk((u32)sv.y);
        a[2] = unpk((u32)zv.z) + sw2 * unpk((u32)sv.z);
        a[3] = unpk((u32)zv.w) + sw2 * unpk((u32)sv.w);
    } else {
#pragma unroll
        for (int j = 0; j < 4; ++j) a[j] = (f32x2){0.f, 0.f};
    }

    int s = offs[node], e = offs[node + 1];
#pragma unroll 4
    for (int p0 = s; p0 < e; p0 += 4) {
        int idx = p0 + eg;
        int idc = min(idx, e - 1);
        int2 q = cwp[idc];
        float wt = (idx < e) ? __int_as_float(q.y) : 0.f;
        f32x2 wt2 = {wt, wt};
        int4 v = *(const int4*)(yzin + (size_t)q.x * 256 + seg * 8);
        a[0] += wt2 * unpk((u32)v.x);
        a[1] += wt2 * unpk((u32)v.y);
        a[2] += wt2 * unpk((u32)v.z);
        a[3] += wt2 * unpk((u32)v.w);
    }

    // reduce the 4 edge-groups
#pragma unroll
    for (int j = 0; j < 4; ++j) {
        a[j].x += __shfl_xor(a[j].x, 16, 64);
        a[j].y += __shfl_xor(a[j].y, 16, 64);
        a[j].x += __shfl_xor(a[j].x, 32, 64);
        a[j].y += __shfl_xor(a[j].y, 32, 64);
    }
    // LN stats over 128 cols
    float s1 = 0.f, s2 = 0.f;
#pragma unroll
    for (int j = 0; j < 4; ++j) {
        s1 += a[j].x + a[j].y;
        s2 += a[j].x * a[j].x + a[j].y * a[j].y;
    }
#pragma unroll
    for (int m = 8; m >= 1; m >>= 1) {
        s1 += __shfl_xor(s1, m, 64);
        s2 += __shfl_xor(s2, m, 64);
    }
    float mu  = s1 * (1.0f / 128);
    float var = s2 * (1.0f / 128) - mu * mu;
    float inv = rsqrtf(var + 1e-5f);
    if (eg == 0) {
        bf16x8 hv, lv;
#pragma unroll
        for (int j = 0; j < 4; ++j) {
            float o0 = fmaxf((a[j].x - mu) * inv, 0.f);
            float o1 = fmaxf((a[j].y - mu) * inv, 0.f);
            u16 h0 = f2bf(o0), h1 = f2bf(o1);
            hv[2 * j]     = (short)h0;
            hv[2 * j + 1] = (short)h1;
            lv[2 * j]     = (short)f2bf(o0 - bf2f(h0));
            lv[2 * j + 1] = (short)f2bf(o1 - bf2f(h1));
        }
        *(bf16x8*)(hout + (size_t)node * 256 + seg * 8)       = hv;
        *(bf16x8*)(hout + (size_t)node * 256 + 128 + seg * 8) = lv;
    }
}

// ---------------------------------------------------------------------------
// B-register-resident GEMM (mid/last): NO LDS, NO barrier.
// ---------------------------------------------------------------------------
template <int HOUT, int OSTR, int WAVES>
__global__ __launch_bounds__(WAVES * 64, 1) void gemm_breg_kernel(
    const u16* __restrict__ hin,
    const u16* __restrict__ Bh, const u16* __restrict__ Bl,
    u16* __restrict__ yzout, int N) {
    constexpr int NTOT = HOUT / 8;           // 16 or 6 B-tiles
    constexpr int TPW  = NTOT / WAVES;       // 2 (HOUT=128) or 1 (HOUT=48)
    int tid = threadIdx.x;
    int w = tid >> 6, lane = tid & 63;
    int c16 = lane & 15, g = lane >> 4, koff = g * 8;
    int m0 = blockIdx.x * ROWS;
    int tmax = min(ROWS, N - m0) >> 4;

    if constexpr (HOUT == 48) {
        for (int i = tid; i < ROWS * 8; i += WAVES * 64) {
            int r = i >> 3, rem = i & 7;
            if (m0 + r < N) {
                int col = 48 + (rem >> 2) * 64 + (rem & 3) * 4;
                bf16x4 zz = (bf16x4){0, 0, 0, 0};
                *(bf16x4*)(yzout + (size_t)(m0 + r) * OSTR + col) = zz;
            }
        }
    }

    bf16x8 bh[TPW][4], bl[TPW][4];
#pragma unroll
    for (int i = 0; i < TPW; ++i) {
        int t = w * TPW + i;
        const u16* pbh = Bh + (size_t)(t * 16 + c16) * 128 + koff;
        const u16* pbl = Bl + (size_t)(t * 16 + c16) * 128 + koff;
#pragma unroll
        for (int k = 0; k < 4; ++k) {
            bh[i][k] = *(const bf16x8*)(pbh + k * 32);
            bl[i][k] = *(const bf16x8*)(pbl + k * 32);
        }
    }

#pragma unroll 2
    for (int t = 0; t < tmax; ++t) {
        int row = m0 + t * 16 + c16;
        const u16* pa = hin + (size_t)row * 256 + koff;
        bf16x8 ah[4], al[4];
#pragma unroll
        for (int k = 0; k < 4; ++k) {
            ah[k] = *(const bf16x8*)(pa + k * 32);
            al[k] = *(const bf16x8*)(pa + 128 + k * 32);
        }
#pragma unroll
        for (int i = 0; i < TPW; ++i) {
            int tt = w * TPW + i;
            f32x4 acc = (f32x4){0.f, 0.f, 0.f, 0.f};
#pragma unroll
            for (int k = 0; k < 4; ++k) {
                acc = __builtin_amdgcn_mfma_f32_16x16x32_bf16(bh[i][k], ah[k], acc, 0, 0, 0);
                acc = __builtin_amdgcn_mfma_f32_16x16x32_bf16(bh[i][k], al[k], acc, 0, 0, 0);
                acc = __builtin_amdgcn_mfma_f32_16x16x32_bf16(bl[i][k], ah[k], acc, 0, 0, 0);
            }
            int colbase = tt * 16 + g * 4;
            if (HOUT == 48 && tt >= 3) colbase += 16;   // z half at col 64
            bf16x4 o;
            o[0] = (short)f2bf(acc[0]);
            o[1] = (short)f2bf(acc[1]);
            o[2] = (short)f2bf(acc[2]);
            o[3] = (short)f2bf(acc[3]);
            *(bf16x4*)(yzout + (size_t)row * OSTR + colbase) = o;
        }
    }
}

// ---------------------------------------------------------------------------
// Layer-1 GEMM: same structure; A-frags converted from f32 x in registers.
// ---------------------------------------------------------------------------
__global__ __launch_bounds__(512, 1) void xgemm_breg_kernel(
    const float* __restrict__ x,
    const u16* __restrict__ Bh, const u16* __restrict__ Bl,
    u16* __restrict__ yzout, int N) {
    int tid = threadIdx.x;
    int w = tid >> 6, lane = tid & 63;
    int c16 = lane & 15, g = lane >> 4, koff = g * 8;
    int m0 = blockIdx.x * ROWS;
    int tmax = min(ROWS, N - m0) >> 4;

    bf16x8 bh[2][4], bl[2][4];
#pragma unroll
    for (int i = 0; i < 2; ++i) {
        int t = w * 2 + i;
        const u16* pbh = Bh + (size_t)(t * 16 + c16) * 128 + koff;
        const u16* pbl = Bl + (size_t)(t * 16 + c16) * 128 + koff;
#pragma unroll
        for (int k = 0; k < 4; ++k) {
            bh[i][k] = *(const bf16x8*)(pbh + k * 32);
            bl[i][k] = *(const bf16x8*)(pbl + k * 32);
        }
    }

#pragma unroll 2
    for (int t = 0; t < tmax; ++t) {
        int row = m0 + t * 16 + c16;
        const float* px = x + (size_t)row * IN_F;
        bf16x8 ah[4], al[4];
#pragma unroll
        for (int k = 0; k < 4; ++k) {
            int c0 = koff + k * 32;
            float4 v0 = (c0 < IN_F)     ? *(const float4*)(px + c0)     : (float4){0.f, 0.f, 0.f, 0.f};
            float4 v1 = (c0 + 4 < IN_F) ? *(const float4*)(px + c0 + 4) : (float4){0.f, 0.f, 0.f, 0.f};
            float f[8] = {v0.x, v0.y, v0.z, v0.w, v1.x, v1.y, v1.z, v1.w};
#pragma unroll
            for (int j = 0; j < 8; ++j) {
                u16 h = f2bf(f[j]);
                ah[k][j] = (short)h;
                al[k][j] = (short)f2bf(f[j] - bf2f(h));
            }
        }
#pragma unroll
        for (int i = 0; i < 2; ++i) {
            int tt = w * 2 + i;
            f32x4 acc = (f32x4){0.f, 0.f, 0.f, 0.f};
#pragma unroll
            for (int k = 0; k < 4; ++k) {
                acc = __builtin_amdgcn_mfma_f32_16x16x32_bf16(bh[i][k], ah[k], acc, 0, 0, 0);
                acc = __builtin_amdgcn_mfma_f32_16x16x32_bf16(bh[i][k], al[k], acc, 0, 0, 0);
                acc = __builtin_amdgcn_mfma_f32_16x16x32_bf16(bl[i][k], ah[k], acc, 0, 0, 0);
            }
            int colbase = tt * 16 + g * 4;
            bf16x4 o;
            o[0] = (short)f2bf(acc[0]);
            o[1] = (short)f2bf(acc[1]);
            o[2] = (short)f2bf(acc[2]);
            o[3] = (short)f2bf(acc[3]);
            *(bf16x4*)(yzout + (size_t)row * 256 + colbase) = o;
        }
    }
}

// ---------------------------------------------------------------------------
// Final: out = LN( gather(y3) + self + z3 ).  yz3 [N][128] bf16:
// y cols 0..47 (pad..63), z cols 64..111.  Wave per node; seg=lane&7, eg=lane>>3.
// f32x2 accumulators -> v_pk_fma_f32.
// ---------------------------------------------------------------------------
__global__ __launch_bounds__(256) void final_reduce_kernel(
    const u16* __restrict__ yz, const int* __restrict__ offs,
    const int2* __restrict__ cwp, const float* __restrict__ dis,
    float* __restrict__ out, int N) {
    int node = (blockIdx.x * 256 + threadIdx.x) >> 6;
    int lane = threadIdx.x & 63;
    if (node >= N) return;
    int seg = lane & 7, eg = lane >> 3;

    f32x2 a[4];
    if (eg == 0) {
        float d = dis[node];
        float sw = 2.f * d * d;
        f32x2 sw2 = {sw, sw};
        int4 sv = *(const int4*)(yz + (size_t)node * 128 + seg * 8);
        int4 zv = *(const int4*)(yz + (size_t)node * 128 + 64 + seg * 8);
        a[0] = unpk((u32)zv.x) + sw2 * unpk((u32)sv.x);
        a[1] = unpk((u32)zv.y) + sw2 * unpk((u32)sv.y);
        a[2] = unpk((u32)zv.z) + sw2 * unpk((u32)sv.z);
        a[3] = unpk((u32)zv.w) + sw2 * unpk((u32)sv.w);
    } else {
#pragma unroll
        for (int j = 0; j < 4; ++j) a[j] = (f32x2){0.f, 0.f};
    }

    int s = offs[node], e = offs[node + 1];
#pragma unroll 4
    for (int p0 = s; p0 < e; p0 += 8) {
        int idx = p0 + eg;
        int idc = min(idx, e - 1);
        int2 q = cwp[idc];
        float wt = (idx < e) ? __int_as_float(q.y) : 0.f;
        f32x2 wt2 = {wt, wt};
        int4 v = *(const int4*)(yz + (size_t)q.x * 128 + seg * 8);
        a[0] += wt2 * unpk((u32)v.x);
        a[1] += wt2 * unpk((u32)v.y);
        a[2] += wt2 * unpk((u32)v.z);
        a[3] += wt2 * unpk((u32)v.w);
    }

#pragma unroll
    for (int j = 0; j < 4; ++j) {
        a[j].x += __shfl_xor(a[j].x, 8, 64);
        a[j].y += __shfl_xor(a[j].y, 8, 64);
        a[j].x += __shfl_xor(a[j].x, 16, 64);
        a[j].y += __shfl_xor(a[j].y, 16, 64);
        a[j].x += __shfl_xor(a[j].x, 32, 64);
        a[j].y += __shfl_xor(a[j].y, 32, 64);
    }
    // LN over the 47 real cols
    float s1 = 0.f, s2 = 0.f;
#pragma unroll
    for (int j = 0; j < 4; ++j) {
        int col0 = seg * 8 + 2 * j;
        if (col0 < OUT_F)     { s1 += a[j].x; s2 += a[j].x * a[j].x; }
        if (col0 + 1 < OUT_F) { s1 += a[j].y; s2 += a[j].y * a[j].y; }
    }
#pragma unroll
    for (int m = 4; m >= 1; m >>= 1) {
        s1 += __shfl_xor(s1, m, 64);
        s2 += __shfl_xor(s2, m, 64);
    }
    float mu  = s1 * (1.0f / OUT_F);
    float var = s2 * (1.0f / OUT_F) - mu * mu;
    float inv = rsqrtf(var + 1e-5f);

    if (eg == 0) {
#pragma unroll
        for (int j = 0; j < 4; ++j) {
            int col0 = seg * 8 + 2 * j;
            if (col0 < OUT_F)
                out[(size_t)node * OUT_F + col0] = (a[j].x - mu) * inv;
            if (col0 + 1 < OUT_F)
                out[(size_t)node * OUT_F + col0 + 1] = (a[j].y - mu) * inv;
        }
    }
}

// ---------------------------------------------------------------------------
extern "C" void kernel_launch(void* const* d_in, const int* in_sizes, int n_in,
                              void* d_out, int out_size, void* d_ws, size_t ws_size,
                              hipStream_t stream) {
    const float* x  = (const float*)d_in[0];
    const int*   ei = (const int*)d_in[1];
    const float* W1 = (const float*)d_in[2];
    const float* W2 = (const float*)d_in[3];
    const float* W3 = (const float*)d_in[4];
    float* out = (float*)d_out;

    const int N = in_sizes[0] / IN_F;   // 50000
    const int E = in_sizes[1] / 2;      // 800000
    const int* erow = ei;
    const int* ecol = ei + E;

    char* p = (char*)d_ws;
    auto alloc = [&](size_t bytes) -> void* {
        void* r = (void*)p;
        p += (bytes + 255) & ~(size_t)255;
        return r;
    };
    int*   cnt  = (int*)  alloc((size_t)N * 4);
    int*   offs = (int*)  alloc((size_t)(N + 1) * 4);
    int*   fill = (int*)  alloc((size_t)N * 4);
    float* dis  = (float*)alloc((size_t)N * 4);
    int*   bsum = (int*)  alloc((size_t)256 * 4);
    int2*  cwp  = (int2*) alloc((size_t)(E + 16) * 8);
    u16*   yzA  = (u16*)  alloc((size_t)N * 256 * 2);   // 25.6 MB
    u16*   yzB  = (u16*)  alloc((size_t)N * 256 * 2);
    u16*   yzC  = (u16*)  alloc((size_t)N * 128 * 2);
    u16*   hbuf = (u16*)  alloc((size_t)N * 256 * 2);   // h hi|lo
    u16*   B1h  = (u16*)  alloc((size_t)256 * 128 * 2);
    u16*   B1l  = (u16*)  alloc((size_t)256 * 128 * 2);
    u16*   B2h  = (u16*)  alloc((size_t)256 * 128 * 2);
    u16*   B2l  = (u16*)  alloc((size_t)256 * 128 * 2);
    u16*   B3h  = (u16*)  alloc((size_t)96 * 128 * 2);
    u16*   B3l  = (u16*)  alloc((size_t)96 * 128 * 2);

    hipMemsetAsync(cnt,  0, (size_t)N * 4, stream);
    hipMemsetAsync(fill, 0, (size_t)N * 4, stream);

    const int egrid = (E + 255) / 256;       // 3125
    const int nb    = (N + 255) / 256;       // 196

    count_kernel<<<egrid, 256, 0, stream>>>(erow, E, cnt);
    scan_bsum_kernel<<<nb, 256, 0, stream>>>(cnt, bsum, N);
    scan_mid_kernel<<<1, 256, 0, stream>>>(bsum, nb);
    scan_offs_kernel<<<nb, 256, 0, stream>>>(cnt, bsum, offs, dis, N, E);
    fill_slice_kernel<<<egrid * 8, 256, 0, stream>>>(erow, ecol, E, offs, fill, dis, cwp, N);

    wtprep_all_kernel<<<608, 128, 0, stream>>>(W1, W2, W3, B1h, B1l, B2h, B2l, B3h, B3l);

    const int gblocks = (N + ROWS - 1) / ROWS;   // 391
    const int wblocks = (N * 64 + 255) / 256;    // 12500 (wave per node)

    // layer 1: x -> yz1
    xgemm_breg_kernel<<<gblocks, 512, 0, stream>>>(x, B1h, B1l, yzA, N);
    // layer 2
    gather_ln_kernel<<<wblocks, 256, 0, stream>>>(yzA, offs, cwp, dis, hbuf, N);
    gemm_breg_kernel<128, 256, 8><<<gblocks, 512, 0, stream>>>(hbuf, B2h, B2l, yzB, N);
    // layer 3
    gather_ln_kernel<<<wblocks, 256, 0, stream>>>(yzB, offs, cwp, dis, hbuf, N);
    gemm_breg_kernel<48, 128, 6><<<gblocks, 384, 0, stream>>>(hbuf, B3h, B3l, yzC, N);
    // final
    final_reduce_kernel<<<wblocks, 256, 0, stream>>>(yzC, offs, cwp, dis, out, N);
}